// Round 2
// baseline (303.689 us; speedup 1.0000x reference)
//
#include <hip/hip_runtime.h>
#include <math.h>

// Router: x[8192,4096] fp32; Wg,Wc[64,4096]; scores=|cls*silu(gate)|, softmax,
// top-8 of scores+bias, weights = 1 + scores*extra_scale (gathered).
// Out: weights [8192,8] fp32, then indices [8192,8] written as float values.
//
// v3: bf16 THREE-way split (hi/mid/lo) MFMA GEMM with 6 cross products
// (hH,hM,mH,hL,lH,mM). Method error ~2^-27 relative on logits -- below fp32
// ulp, so ordering noise reduces to fp32 accumulation-order noise, the same
// scale as the fp32 vector kernel that passed absmax 0. (v2's 2-way split had
// ~2^-18 method error -> a few rank-8/9 flips -> indices absmax 31.)
// Shape: mfma_f32_32x32x16_bf16 (2382 TF rate, fewest instructions).
// No LDS, no barriers; A prefetched 1 k-step ahead in named registers.

#define T_DIM 8192
#define D_DIM 4096
#define E_DIM 64
#define N2    128      // 64 gate cols + 64 cls cols
#define KTOP  8
#define MB_ROWS 128    // rows per workgroup (4 waves x 32 rows)

typedef __attribute__((ext_vector_type(8)))  short bfrag8;   // 8 bf16 (4 VGPRs)
typedef __attribute__((ext_vector_type(16))) float f32x16;   // 32x32 C/D frag

__device__ __forceinline__ unsigned short f2bf_rne(float f) {
    unsigned int u = __float_as_uint(f);
    unsigned int r = u + 0x7fffu + ((u >> 16) & 1u);        // round-nearest-even
    return (unsigned short)(r >> 16);
}
__device__ __forceinline__ float bf2f(unsigned short h) {
    return __uint_as_float(((unsigned int)h) << 16);
}
// v = bf2f(h) + bf2f(m) + bf2f(l) + eps, |eps| <= 2^-27 |v|
__device__ __forceinline__ void split3(float v, unsigned short& h,
                                       unsigned short& m, unsigned short& l) {
    h = f2bf_rne(v);
    const float r1 = v - bf2f(h);          // exact in fp32
    m = f2bf_rne(r1);
    const float r2 = r1 - bf2f(m);         // exact in fp32
    l = f2bf_rne(r2);
}

// ---------------- Kernel 0: W -> Whi + Wmid + Wlo (bf16), row-major [128][4096]
// cols 0..63 = gate (Wg), 64..127 = cls (Wc). 3 MB total -> L2-resident.
__global__ __launch_bounds__(256)
void router_prep(const float* __restrict__ Wg, const float* __restrict__ Wc,
                 unsigned short* __restrict__ Whi, unsigned short* __restrict__ Wmid,
                 unsigned short* __restrict__ Wlo)
{
    const int i   = blockIdx.x * 256 + threadIdx.x;  // float4 index, 131072 total
    const int row = i >> 10;                         // 1024 float4 per row
    const float* src = (row < E_DIM) ? (Wg + (size_t)row * D_DIM)
                                     : (Wc + (size_t)(row - E_DIM) * D_DIM);
    const float4 w = ((const float4*)src)[i & 1023];
    const float v[4] = {w.x, w.y, w.z, w.w};
    ushort4 hv, mv, lv;
    split3(v[0], hv.x, mv.x, lv.x);
    split3(v[1], hv.y, mv.y, lv.y);
    split3(v[2], hv.z, mv.z, lv.z);
    split3(v[3], hv.w, mv.w, lv.w);
    *(ushort4*)(Whi  + (size_t)i * 4) = hv;
    *(ushort4*)(Wmid + (size_t)i * 4) = mv;
    *(ushort4*)(Wlo  + (size_t)i * 4) = lv;
}

// ---------------- Kernel 1: 3-way-split MFMA GEMM, partials P[ks][T][128] ------
// Block: 256 thr = 4 waves; wave = one 32-row M-tile x all 128 cols (4 N-tiles).
// Grid: (64 M-blocks, S K-slices). 32x32x16 frags: A lane row = lane&31,
// k = (lane>>5)*8 + j (8 contiguous); B lane col = lane&31, same k -> 16B
// contiguous loads from row-major Whi/Wmid/Wlo (L1-hot, shared by all waves).
// C/D (m74/m101-verified): col = lane&31, row = (r&3) + 8*(r>>2) + 4*(lane>>5).
__global__ __launch_bounds__(256, 2)
void router_gemm(const float* __restrict__ x,
                 const unsigned short* __restrict__ Whi,
                 const unsigned short* __restrict__ Wmid,
                 const unsigned short* __restrict__ Wlo,
                 float* __restrict__ P,
                 int sliceK)
{
    const int tid  = threadIdx.x;
    const int lane = tid & 63;
    const int wid  = tid >> 6;
    const int l31  = lane & 31;
    const int lh   = lane >> 5;          // k-group (0/1)
    const int mb   = blockIdx.x;
    const int ks   = blockIdx.y;
    const int k0   = ks * sliceK;
    const int kend = k0 + sliceK;
    const int row0 = mb * MB_ROWS + wid * 32;

    f32x16 acc[4];
    #pragma unroll
    for (int n = 0; n < 4; ++n)
        #pragma unroll
        for (int r = 0; r < 16; ++r)
            acc[n][r] = 0.f;

    const float* xr = x + (size_t)(row0 + l31) * D_DIM;

    // prefetched A tile: 16 floats (two k-halves of 8), named registers only
    const float* xp0 = xr + k0 + lh * 8;
    float4 a00 = *(const float4*)(xp0);
    float4 a01 = *(const float4*)(xp0 + 4);
    float4 a10 = *(const float4*)(xp0 + 16);
    float4 a11 = *(const float4*)(xp0 + 20);

    for (int kk = k0; kk < kend; kk += 32) {
        // split current A tile to bf16 hi/mid/lo fragments
        bfrag8 ah[2], am[2], al[2];
        {
            const float av0[8] = {a00.x,a00.y,a00.z,a00.w,a01.x,a01.y,a01.z,a01.w};
            const float av1[8] = {a10.x,a10.y,a10.z,a10.w,a11.x,a11.y,a11.z,a11.w};
            #pragma unroll
            for (int j = 0; j < 8; ++j) {
                unsigned short h, m, l;
                split3(av0[j], h, m, l);
                ah[0][j] = (short)h; am[0][j] = (short)m; al[0][j] = (short)l;
                split3(av1[j], h, m, l);
                ah[1][j] = (short)h; am[1][j] = (short)m; al[1][j] = (short)l;
            }
        }

        // issue next-iteration A loads; latency hides under 48 MFMAs + B loads
        if (kk + 32 < kend) {
            const float* xp = xr + (kk + 32) + lh * 8;
            a00 = *(const float4*)(xp);
            a01 = *(const float4*)(xp + 4);
            a10 = *(const float4*)(xp + 16);
            a11 = *(const float4*)(xp + 20);
        }

        #pragma unroll
        for (int n = 0; n < 4; ++n) {
            #pragma unroll
            for (int h2 = 0; h2 < 2; ++h2) {
                const size_t bo = (size_t)(n * 32 + l31) * D_DIM + kk + h2 * 16 + lh * 8;
                const bfrag8 bh = *(const bfrag8*)(Whi  + bo);
                const bfrag8 bm = *(const bfrag8*)(Wmid + bo);
                const bfrag8 bl = *(const bfrag8*)(Wlo  + bo);
                // smallest products first (better fp32 accumulation)
                acc[n] = __builtin_amdgcn_mfma_f32_32x32x16_bf16(ah[h2], bl, acc[n], 0, 0, 0);
                acc[n] = __builtin_amdgcn_mfma_f32_32x32x16_bf16(al[h2], bh, acc[n], 0, 0, 0);
                acc[n] = __builtin_amdgcn_mfma_f32_32x32x16_bf16(am[h2], bm, acc[n], 0, 0, 0);
                acc[n] = __builtin_amdgcn_mfma_f32_32x32x16_bf16(ah[h2], bm, acc[n], 0, 0, 0);
                acc[n] = __builtin_amdgcn_mfma_f32_32x32x16_bf16(am[h2], bh, acc[n], 0, 0, 0);
                acc[n] = __builtin_amdgcn_mfma_f32_32x32x16_bf16(ah[h2], bh, acc[n], 0, 0, 0);
            }
        }
    }

    // store partial C tile: P[ks][row][col]
    float* Pb = P + ((size_t)ks * T_DIM + row0) * N2 + l31;
    #pragma unroll
    for (int n = 0; n < 4; ++n)
        #pragma unroll
        for (int r = 0; r < 16; ++r) {
            const int wrow = (r & 3) + 8 * (r >> 2) + 4 * lh;
            Pb[(size_t)wrow * N2 + n * 32] = acc[n][r];
        }
}

// ---------------- Kernel 2: reduce slices + silu/abs/softmax + biased top-8 ----
// (unchanged from the passing kernel — exact index ordering proven)
__global__ __launch_bounds__(256)
void router_topk(const float* __restrict__ P,
                 const float* __restrict__ scale,
                 const float* __restrict__ bias,
                 float* __restrict__ out,
                 int ksplit)
{
    const int lane = threadIdx.x & 63;   // expert id
    const int wid  = threadIdx.x >> 6;
    const int row  = blockIdx.x * 4 + wid;

    float g = 0.f, c = 0.f;
    for (int ks = 0; ks < ksplit; ++ks) {
        const float* p = P + ((size_t)ks * T_DIM + row) * N2;
        g += p[lane];
        c += p[E_DIM + lane];
    }
    const float sg = g / (1.f + expf(-g));   // silu(gate)
    const float v  = fabsf(c * sg);          // score pre-softmax

    // fp32 softmax across the 64 lanes
    float m = v;
    #pragma unroll
    for (int off = 32; off >= 1; off >>= 1) m = fmaxf(m, __shfl_xor(m, off));
    const float e = expf(v - m);
    float Z = e;
    #pragma unroll
    for (int off = 32; off >= 1; off >>= 1) Z += __shfl_xor(Z, off);
    const float s = e / Z;

    const float sc  = scale[lane];
    float cur = s + bias[lane];              // selection key

    float myw = 0.f; int myi = 0;
    #pragma unroll
    for (int j = 0; j < KTOP; ++j) {
        // wave argmax, ties -> lowest index (matches jax.lax.top_k)
        float bv = cur; int bi = lane;
        #pragma unroll
        for (int off = 32; off >= 1; off >>= 1) {
            const float ov = __shfl_xor(bv, off);
            const int   oi = __shfl_xor(bi, off);
            if (ov > bv || (ov == bv && oi < bi)) { bv = ov; bi = oi; }
        }
        const float s_bi  = __shfl(s,  bi);
        const float sc_bi = __shfl(sc, bi);
        const float w = 1.f + s_bi * sc_bi;  // "original" gathered at bi
        if (lane == j)  { myw = w; myi = bi; }
        if (lane == bi) cur = -INFINITY;
    }

    if (lane < KTOP) {
        out[(size_t)row * KTOP + lane] = myw;
        out[(size_t)T_DIM * KTOP + (size_t)row * KTOP + lane] = (float)myi;
    }
}

extern "C" void kernel_launch(void* const* d_in, const int* in_sizes, int n_in,
                              void* d_out, int out_size, void* d_ws, size_t ws_size,
                              hipStream_t stream)
{
    const float* x  = (const float*)d_in[0];
    const float* Wg = (const float*)d_in[1];
    const float* Wc = (const float*)d_in[2];
    const float* sc = (const float*)d_in[3];
    const float* bs = (const float*)d_in[4];
    float* out = (float*)d_out;
    float* P   = (float*)d_ws;

    const size_t PER = (size_t)T_DIM * N2 * sizeof(float);           // 4 MB per slice
    const size_t WSP = (size_t)N2 * D_DIM * sizeof(unsigned short);  // 1 MB per W part

    // Need S*4MB (partials) + 3MB (W split); degrade gracefully if ws is small.
    int S = 8;
    while (S > 1 && (size_t)S * PER + 3 * WSP > ws_size) S >>= 1;
    const int sliceK = D_DIM / S;

    unsigned short* Whi  = (unsigned short*)((char*)d_ws + (size_t)S * PER);
    unsigned short* Wmid = Whi + (size_t)N2 * D_DIM;
    unsigned short* Wlo  = Wmid + (size_t)N2 * D_DIM;

    router_prep<<<512, 256, 0, stream>>>(Wg, Wc, Whi, Wmid, Wlo);
    router_gemm<<<dim3(T_DIM / MB_ROWS, S), 256, 0, stream>>>(x, Whi, Wmid, Wlo, P, sliceK);
    router_topk<<<T_DIM / 4, 256, 0, stream>>>(P, sc, bs, out, S);
}